// Round 2
// baseline (683.438 us; speedup 1.0000x reference)
//
#include <hip/hip_runtime.h>
#include <hip/hip_fp16.h>

// 2-branch PolyConv GNN + MLP head. float32, int32 indices.
// f_k = L^k h, L(f) = f - dinv*S(f*dinv). Filters = linear combos of f_0,f_1,f_2:
//   ortho: o0 = 3f0-3f1+0.75f2, o1 = 3f1-1.5f2, o2 = 0.75f2
//   sim:   all three = 4(f0+f1+f2)
// R9 changes vs R8:
//  (1) fill2 (123us, WRITE_SIZE 107MB line-thrash) replaced by bucketed 2-phase
//      fill: bin edges into 32-node buckets (bucket segment bounds come free
//      from row[]), then per-bucket place with LDS cursors. Both passes write
//      sequentially within hot regions -> writes merge in L2 (~13MB total).
//      row[] is no longer destroyed; readers use row[d]..row[d+1].
//  (2) dinv folded into fp16 shadows (h16 = relu*dinv, g16 = f1*dinv) ->
//      per-edge dinv load gone; hop inner loop is a pure fp16 gather-sum.
//  (3) hop gathers unrolled 8-wide (latency-bound, more outstanding loads).
// hall slots (stride 384): ortho f0/f1/f2 -> 0/64/128, sim -> 192/256/320.
// dinv (2N f32) lives in logits region (overwritten by MLP last).
// d_ws: row_o[N+1] row_s[N+1] cnt[2N] esrc_o[E] esrc_s[Es] part[2B] bcur[2K]
//       h16_o[N*64] h16_s[N*64] g16_o[N*64] g16_s[N*64]  (halves)
//       staged[E+Es] aliases g16 (g16 written only later, in hop1).

__global__ __launch_bounds__(256) void count2_kernel(
    const int* __restrict__ dst, const int* __restrict__ sim_dst,
    int* __restrict__ cnt, int N, int E, int Es) {
    int e = blockIdx.x * 256 + threadIdx.x;
    if (e < E) atomicAdd(&cnt[dst[e]], 1);
    else if (e < E + Es) atomicAdd(&cnt[N + sim_dst[e - E]], 1);
}

// Phase 1: per-1024-chunk sums. grid = 2*B, cnt = [graph0 N | graph1 N].
// Also zeroes the bucket cursors for bin2 (runs before it on the stream).
__global__ __launch_bounds__(256) void scan_p1(const int* __restrict__ cnt,
                                               int* __restrict__ part,
                                               int* __restrict__ bcur, int K2,
                                               int N, int B) {
    int gi = blockIdx.x * 256 + threadIdx.x;
    if (gi < K2) bcur[gi] = 0;
    int g = blockIdx.x / B, c = blockIdx.x - g * B;
    const int* p = cnt + (long)g * N;
    int tid = threadIdx.x, base = c << 10;
    int s = 0;
    #pragma unroll
    for (int q = 0; q < 4; ++q) {
        int i = base + q * 256 + tid;
        if (i < N) s += p[i];
    }
    #pragma unroll
    for (int off = 32; off > 0; off >>= 1) s += __shfl_down(s, off);
    __shared__ int ws[4];
    if ((tid & 63) == 0) ws[tid >> 6] = s;
    __syncthreads();
    if (tid == 0) part[blockIdx.x] = ws[0] + ws[1] + ws[2] + ws[3];
}

// Phase 2: exclusive scan of B partials per graph (B <= 64). grid = 2 x 64.
__global__ __launch_bounds__(64) void scan_p2(int* __restrict__ part,
                                              int* __restrict__ row_o,
                                              int* __restrict__ row_s, int N, int B) {
    int g = blockIdx.x, t = threadIdx.x;
    int v = (t < B) ? part[g * B + t] : 0;
    int inc = v;
    #pragma unroll
    for (int off = 1; off < 64; off <<= 1) {
        int u = __shfl_up(inc, off);
        if (t >= off) inc += u;
    }
    if (t < B) part[g * B + t] = inc - v;          // exclusive chunk offsets
    int total = __shfl(inc, 63);
    if (t == 0) (g == 0 ? row_o : row_s)[N] = total;
}

// Phase 3: block-local exclusive scan + chunk offset -> row; dinv fused.
__global__ __launch_bounds__(256) void scan_p3(const int* __restrict__ cnt,
                                               const int* __restrict__ part,
                                               int* __restrict__ row_o, int* __restrict__ row_s,
                                               float* __restrict__ dinv, int N, int B) {
    int g = blockIdx.x / B, c = blockIdx.x - g * B;
    int tid = threadIdx.x;
    int base = (c << 10) + tid * 4;
    const int* p = cnt + (long)g * N;
    int* row = (g == 0) ? row_o : row_s;
    float* dv = dinv + (long)g * N;
    int v[4];
    #pragma unroll
    for (int q = 0; q < 4; ++q) { int i = base + q; v[q] = (i < N) ? p[i] : 0; }
    int s = v[0] + v[1] + v[2] + v[3];
    int inc = s;
    #pragma unroll
    for (int off = 1; off < 64; off <<= 1) {
        int u = __shfl_up(inc, off);
        if ((tid & 63) >= off) inc += u;
    }
    __shared__ int wt[4];
    if ((tid & 63) == 63) wt[tid >> 6] = inc;
    __syncthreads();
    int wo = 0;
    for (int w = 0; w < (tid >> 6); ++w) wo += wt[w];
    int ex = part[blockIdx.x] + wo + inc - s;
    #pragma unroll
    for (int q = 0; q < 4; ++q) {
        int i = base + q;
        if (i < N) {
            row[i] = ex;
            dv[i] = rsqrtf((float)(v[q] > 1 ? v[q] : 1));
            ex += v[q];
        }
    }
}

// Bin pass: scatter packed (src<<5 | dst&31) into 32-node bucket segments.
// Bucket b's segment = [row[b*32], row[b*32+32]) -- bounds come from row.
// Writes to a bucket are sequential in time+address -> L2 merges lines.
__global__ __launch_bounds__(256) void bin2_kernel(
    const int* __restrict__ src, const int* __restrict__ dst,
    const int* __restrict__ sim_src, const int* __restrict__ sim_dst,
    const int* __restrict__ row_o, const int* __restrict__ row_s,
    int* __restrict__ bcur, int* __restrict__ staged, int K, int E, int Es) {
    int e = blockIdx.x * 256 + threadIdx.x;
    if (e < E) {
        int d = dst[e];
        int b = d >> 5;
        int pos = row_o[b << 5] + atomicAdd(&bcur[b], 1);
        staged[pos] = (src[e] << 5) | (d & 31);
    } else if (e < E + Es) {
        int e2 = e - E;
        int d = sim_dst[e2];
        int b = d >> 5;
        int pos = row_s[b << 5] + atomicAdd(&bcur[K + b], 1);
        staged[E + pos] = (sim_src[e2] << 5) | (d & 31);
    }
}

// Place pass: one block per bucket; LDS cursors for its 32 nodes; reads the
// staged segment coalesced, writes esrc within the bucket's ~2KB window.
__global__ __launch_bounds__(256) void place_kernel(
    const int* __restrict__ row_o, const int* __restrict__ row_s,
    const int* __restrict__ staged,
    int* __restrict__ esrc_o, int* __restrict__ esrc_s, int N, int K, int E) {
    int b = blockIdx.x;
    const int* row; const int* st; int* esrc;
    if (b < K) { row = row_o; st = staged; esrc = esrc_o; }
    else { b -= K; row = row_s; st = staged + E; esrc = esrc_s; }
    int node0 = b << 5;
    int hi_node = (node0 + 32 < N) ? node0 + 32 : N;
    __shared__ int cur[32];
    int tid = threadIdx.x;
    if (tid < 32) cur[tid] = (node0 + tid < N) ? row[node0 + tid] : 0;
    __syncthreads();
    int lo = row[node0], hi = row[hi_node];
    for (int j = lo + tid; j < hi; j += 256) {
        int v = st[j];
        int pos = atomicAdd(&cur[v & 31], 1);
        esrc[pos] = v >> 5;
    }
}

// Tiled: out[node*384+off+j] = relu(x[node,:]@W[:,j] + b[j]); K=128.
// Also writes fp16 shadow h16[node*64+j] = relu(...)*dinv[node] (premultiplied).
__global__ __launch_bounds__(256) void in_gemm_kernel(
    const float* __restrict__ x, const float* __restrict__ W,
    const float* __restrict__ b, float* __restrict__ out, int off,
    __half* __restrict__ h16, const float* __restrict__ dinvv, int n) {
    __shared__ float xs[64][132];
    __shared__ float Wf[128][68];
    int tid = threadIdx.x;
    int node0 = blockIdx.x * 64;
    const float4* wsrc = (const float4*)W;
    for (int i = tid; i < 2048; i += 256)
        *(float4*)&Wf[i >> 4][(i & 15) * 4] = wsrc[i];
    const float4* xsrc = (const float4*)x;
    for (int i = tid; i < 2048; i += 256) {
        int nl = i >> 5, c = i & 31;
        int node = node0 + nl;
        float4 v = make_float4(0.f, 0.f, 0.f, 0.f);
        if (node < n) v = xsrc[(long)node * 32 + c];
        *(float4*)&xs[nl][c * 4] = v;
    }
    __syncthreads();
    int tx = tid & 15, ty = tid >> 4;
    float acc[4][4] = {};
    #pragma unroll 2
    for (int k = 0; k < 128; k += 4) {
        float4 a[4], bb[4];
        #pragma unroll
        for (int i = 0; i < 4; ++i) a[i] = *(const float4*)&xs[ty * 4 + i][k];
        #pragma unroll
        for (int j = 0; j < 4; ++j) bb[j] = *(const float4*)&Wf[k + j][tx * 4];
        #pragma unroll
        for (int i = 0; i < 4; ++i) {
            acc[i][0] = fmaf(a[i].x, bb[0].x, acc[i][0]);
            acc[i][1] = fmaf(a[i].x, bb[0].y, acc[i][1]);
            acc[i][2] = fmaf(a[i].x, bb[0].z, acc[i][2]);
            acc[i][3] = fmaf(a[i].x, bb[0].w, acc[i][3]);
            acc[i][0] = fmaf(a[i].y, bb[1].x, acc[i][0]);
            acc[i][1] = fmaf(a[i].y, bb[1].y, acc[i][1]);
            acc[i][2] = fmaf(a[i].y, bb[1].z, acc[i][2]);
            acc[i][3] = fmaf(a[i].y, bb[1].w, acc[i][3]);
            acc[i][0] = fmaf(a[i].z, bb[2].x, acc[i][0]);
            acc[i][1] = fmaf(a[i].z, bb[2].y, acc[i][1]);
            acc[i][2] = fmaf(a[i].z, bb[2].z, acc[i][2]);
            acc[i][3] = fmaf(a[i].z, bb[2].w, acc[i][3]);
            acc[i][0] = fmaf(a[i].w, bb[3].x, acc[i][0]);
            acc[i][1] = fmaf(a[i].w, bb[3].y, acc[i][1]);
            acc[i][2] = fmaf(a[i].w, bb[3].z, acc[i][2]);
            acc[i][3] = fmaf(a[i].w, bb[3].w, acc[i][3]);
        }
    }
    float4 bias = *(const float4*)&b[tx * 4];
    #pragma unroll
    for (int i = 0; i < 4; ++i) {
        int node = node0 + ty * 4 + i;
        if (node >= n) break;
        float4 r;
        r.x = fmaxf(acc[i][0] + bias.x, 0.0f);
        r.y = fmaxf(acc[i][1] + bias.y, 0.0f);
        r.z = fmaxf(acc[i][2] + bias.z, 0.0f);
        r.w = fmaxf(acc[i][3] + bias.w, 0.0f);
        *(float4*)&out[(long)node * 384 + off + tx * 4] = r;
        if (h16) {
            float dvn = dinvv[node];
            __half hh[4];
            hh[0] = __float2half_rn(r.x * dvn);
            hh[1] = __float2half_rn(r.y * dvn);
            hh[2] = __float2half_rn(r.z * dvn);
            hh[3] = __float2half_rn(r.w * dvn);
            *(float2*)&h16[(long)node * 64 + tx * 4] = *(float2*)hh;
        }
    }
}

// Hop 1, both graphs merged. Gathers premultiplied fp16 h16 (= h*dinv), so the
// inner loop is a pure sum. Writes f1 fp32 -> hall base+64, f1*dinv fp16 -> g16.
__global__ __launch_bounds__(256) void hop1_kernel(
    const int* __restrict__ row_o, const int* __restrict__ esrc_o, const float* __restrict__ dinv_o,
    const int* __restrict__ row_s, const int* __restrict__ esrc_s, const float* __restrict__ dinv_s,
    const __half* __restrict__ h16_o, const __half* __restrict__ h16_s,
    __half* __restrict__ g16_o, __half* __restrict__ g16_s,
    float* __restrict__ hall, int n, int nb) {
    int b = blockIdx.x;
    const int* row; const int* esrc; const float* dinv; const __half* h16; __half* g16; int base;
    if (b < nb) { row = row_o; esrc = esrc_o; dinv = dinv_o; h16 = h16_o; g16 = g16_o; base = 0; }
    else { b -= nb; row = row_s; esrc = esrc_s; dinv = dinv_s; h16 = h16_s; g16 = g16_s; base = 192; }
    int d = b * 4 + (threadIdx.x >> 6);
    if (d >= n) return;
    int lane = threadIdx.x & 63;
    int p = row[d], end = row[d + 1];
    long ob = (long)d * 384 + lane;
    float dd = dinv[d];
    float f0 = hall[ob + base];
    float a0 = 0.f, a1 = 0.f, a2 = 0.f, a3 = 0.f;
    for (; p + 8 <= end; p += 8) {
        int s0 = esrc[p], s1 = esrc[p + 1], s2 = esrc[p + 2], s3 = esrc[p + 3];
        int s4 = esrc[p + 4], s5 = esrc[p + 5], s6 = esrc[p + 6], s7 = esrc[p + 7];
        a0 += __half2float(h16[(long)s0 * 64 + lane]);
        a1 += __half2float(h16[(long)s1 * 64 + lane]);
        a2 += __half2float(h16[(long)s2 * 64 + lane]);
        a3 += __half2float(h16[(long)s3 * 64 + lane]);
        a0 += __half2float(h16[(long)s4 * 64 + lane]);
        a1 += __half2float(h16[(long)s5 * 64 + lane]);
        a2 += __half2float(h16[(long)s6 * 64 + lane]);
        a3 += __half2float(h16[(long)s7 * 64 + lane]);
    }
    for (; p < end; ++p) {
        int s = esrc[p];
        a0 += __half2float(h16[(long)s * 64 + lane]);
    }
    float acc = (a0 + a1) + (a2 + a3);
    float f1 = f0 - acc * dd;
    hall[ob + base + 64] = f1;
    g16[(long)d * 64 + lane] = __float2half_rn(f1 * dd);
}

// Hop 2 + fused theta-combine. Gathers premultiplied fp16 g16 (in ws), so every
// hall row is touched only by its own wave -> race-free overwrite.
__global__ __launch_bounds__(256) void hop2_kernel(
    const int* __restrict__ row_o, const int* __restrict__ esrc_o, const float* __restrict__ dinv_o,
    const int* __restrict__ row_s, const int* __restrict__ esrc_s, const float* __restrict__ dinv_s,
    const __half* __restrict__ g16_o, const __half* __restrict__ g16_s,
    float* __restrict__ hall, int n, int nb) {
    int b = blockIdx.x;
    bool ortho = b < nb;
    const int* row; const int* esrc; const float* dinv; const __half* g16; int base;
    if (ortho) { row = row_o; esrc = esrc_o; dinv = dinv_o; g16 = g16_o; base = 0; }
    else { b -= nb; row = row_s; esrc = esrc_s; dinv = dinv_s; g16 = g16_s; base = 192; }
    int d = b * 4 + (threadIdx.x >> 6);
    if (d >= n) return;
    int lane = threadIdx.x & 63;
    int p = row[d], end = row[d + 1];
    long ob = (long)d * 384 + lane;
    float dd = dinv[d];
    float f0 = hall[ob + base];
    float f1 = hall[ob + base + 64];
    float a0 = 0.f, a1 = 0.f, a2 = 0.f, a3 = 0.f;
    for (; p + 8 <= end; p += 8) {
        int s0 = esrc[p], s1 = esrc[p + 1], s2 = esrc[p + 2], s3 = esrc[p + 3];
        int s4 = esrc[p + 4], s5 = esrc[p + 5], s6 = esrc[p + 6], s7 = esrc[p + 7];
        a0 += __half2float(g16[(long)s0 * 64 + lane]);
        a1 += __half2float(g16[(long)s1 * 64 + lane]);
        a2 += __half2float(g16[(long)s2 * 64 + lane]);
        a3 += __half2float(g16[(long)s3 * 64 + lane]);
        a0 += __half2float(g16[(long)s4 * 64 + lane]);
        a1 += __half2float(g16[(long)s5 * 64 + lane]);
        a2 += __half2float(g16[(long)s6 * 64 + lane]);
        a3 += __half2float(g16[(long)s7 * 64 + lane]);
    }
    for (; p < end; ++p) {
        int s = esrc[p];
        a0 += __half2float(g16[(long)s * 64 + lane]);
    }
    float acc = (a0 + a1) + (a2 + a3);
    float f2 = f1 - acc * dd;
    if (ortho) {
        hall[ob]       = 3.0f * f0 - 3.0f * f1 + 0.75f * f2;
        hall[ob + 64]  = 3.0f * f1 - 1.5f * f2;
        hall[ob + 128] = 0.75f * f2;
    } else {
        float ss = 4.0f * (f0 + f1 + f2);
        hall[ob + 192] = ss; hall[ob + 256] = ss; hall[ob + 320] = ss;
    }
}

// ---------- fallback path (ws too small for fp16 shadows) ----------
__global__ __launch_bounds__(256) void gather2_kernel(
    const int* __restrict__ row_o, const int* __restrict__ esrc_o, const float* __restrict__ dinv_o,
    const int* __restrict__ row_s, const int* __restrict__ esrc_s, const float* __restrict__ dinv_s,
    float* __restrict__ hall, int in_off_o, int in_off_s, int n, int nb) {
    int b = blockIdx.x;
    const int* row; const int* esrc; const float* dinv; int in_off;
    if (b < nb) { row = row_o; esrc = esrc_o; dinv = dinv_o; in_off = in_off_o; }
    else { b -= nb; row = row_s; esrc = esrc_s; dinv = dinv_s; in_off = in_off_s; }
    int d = b * 4 + (threadIdx.x >> 6);
    if (d >= n) return;
    int lane = threadIdx.x & 63;
    int p = row[d], end = row[d + 1];
    const float* fin = hall + in_off;
    float a0 = 0.f, a1 = 0.f, a2 = 0.f, a3 = 0.f;
    for (; p + 4 <= end; p += 4) {
        int s0 = esrc[p], s1 = esrc[p + 1], s2 = esrc[p + 2], s3 = esrc[p + 3];
        a0 = fmaf(fin[(long)s0 * 384 + lane], dinv[s0], a0);
        a1 = fmaf(fin[(long)s1 * 384 + lane], dinv[s1], a1);
        a2 = fmaf(fin[(long)s2 * 384 + lane], dinv[s2], a2);
        a3 = fmaf(fin[(long)s3 * 384 + lane], dinv[s3], a3);
    }
    for (; p < end; ++p) {
        int s = esrc[p];
        a0 = fmaf(fin[(long)s * 384 + lane], dinv[s], a0);
    }
    float acc = (a0 + a1) + (a2 + a3);
    long ob = (long)d * 384 + lane;
    hall[ob + in_off + 64] = fin[ob] - acc * dinv[d];
}

__global__ __launch_bounds__(256) void combine_kernel(float* __restrict__ h, int nf) {
    int i = blockIdx.x * 256 + threadIdx.x;
    if (i >= nf) return;
    long ob = (long)(i >> 6) * 384 + (i & 63);
    float f0v = h[ob], f1v = h[ob + 64], f2v = h[ob + 128];
    h[ob]       = 3.0f * f0v - 3.0f * f1v + 0.75f * f2v;
    h[ob + 64]  = 3.0f * f1v - 1.5f * f2v;
    h[ob + 128] = 0.75f * f2v;
    float ss = 4.0f * (h[ob + 192] + h[ob + 256] + h[ob + 320]);
    h[ob + 192] = ss; h[ob + 256] = ss; h[ob + 320] = ss;
}
// -------------------------------------------------------------------

// logits = relu(h_all @ Wm1 + bm1) @ Wm2 + bm2. Tiled, K=384 in 3 chunks.
__global__ __launch_bounds__(256) void mlp_kernel(
    const float* __restrict__ hall, const float* __restrict__ Wm1,
    const float* __restrict__ bm1, const float* __restrict__ Wm2,
    const float* __restrict__ bm2, float* __restrict__ logits, int n) {
    __shared__ float xs[64][132];
    __shared__ float Wf[128][68];
    int tid = threadIdx.x;
    int node0 = blockIdx.x * 64;
    int tx = tid & 15, ty = tid >> 4;
    float acc[4][4] = {};
    const float4* wsrc = (const float4*)Wm1;
    const float4* hsrc = (const float4*)hall;
    for (int c = 0; c < 3; ++c) {
        __syncthreads();
        for (int i = tid; i < 2048; i += 256)
            *(float4*)&Wf[i >> 4][(i & 15) * 4] = wsrc[c * 2048 + i];
        for (int i = tid; i < 2048; i += 256) {
            int nl = i >> 5, cc = i & 31;
            int node = node0 + nl;
            float4 v = make_float4(0.f, 0.f, 0.f, 0.f);
            if (node < n) v = hsrc[(long)node * 96 + c * 32 + cc];
            *(float4*)&xs[nl][cc * 4] = v;
        }
        __syncthreads();
        #pragma unroll 2
        for (int k = 0; k < 128; k += 4) {
            float4 a[4], bb[4];
            #pragma unroll
            for (int i = 0; i < 4; ++i) a[i] = *(const float4*)&xs[ty * 4 + i][k];
            #pragma unroll
            for (int j = 0; j < 4; ++j) bb[j] = *(const float4*)&Wf[k + j][tx * 4];
            #pragma unroll
            for (int i = 0; i < 4; ++i) {
                acc[i][0] = fmaf(a[i].x, bb[0].x, acc[i][0]);
                acc[i][1] = fmaf(a[i].x, bb[0].y, acc[i][1]);
                acc[i][2] = fmaf(a[i].x, bb[0].z, acc[i][2]);
                acc[i][3] = fmaf(a[i].x, bb[0].w, acc[i][3]);
                acc[i][0] = fmaf(a[i].y, bb[1].x, acc[i][0]);
                acc[i][1] = fmaf(a[i].y, bb[1].y, acc[i][1]);
                acc[i][2] = fmaf(a[i].y, bb[1].z, acc[i][2]);
                acc[i][3] = fmaf(a[i].y, bb[1].w, acc[i][3]);
                acc[i][0] = fmaf(a[i].z, bb[2].x, acc[i][0]);
                acc[i][1] = fmaf(a[i].z, bb[2].y, acc[i][1]);
                acc[i][2] = fmaf(a[i].z, bb[2].z, acc[i][2]);
                acc[i][3] = fmaf(a[i].z, bb[2].w, acc[i][3]);
                acc[i][0] = fmaf(a[i].w, bb[3].x, acc[i][0]);
                acc[i][1] = fmaf(a[i].w, bb[3].y, acc[i][1]);
                acc[i][2] = fmaf(a[i].w, bb[3].z, acc[i][2]);
                acc[i][3] = fmaf(a[i].w, bb[3].w, acc[i][3]);
            }
        }
    }
    __syncthreads();
    float4 bias = *(const float4*)&bm1[tx * 4];
    #pragma unroll
    for (int i = 0; i < 4; ++i) {
        xs[ty * 4 + i][tx * 4 + 0] = fmaxf(acc[i][0] + bias.x, 0.0f);
        xs[ty * 4 + i][tx * 4 + 1] = fmaxf(acc[i][1] + bias.y, 0.0f);
        xs[ty * 4 + i][tx * 4 + 2] = fmaxf(acc[i][2] + bias.z, 0.0f);
        xs[ty * 4 + i][tx * 4 + 3] = fmaxf(acc[i][3] + bias.w, 0.0f);
    }
    __syncthreads();
    if (tid < 128) {
        int nl = tid >> 1, o = tid & 1;
        int node = node0 + nl;
        if (node < n) {
            float p = bm2[o];
            #pragma unroll 8
            for (int k = 0; k < 64; ++k) p = fmaf(xs[nl][k], Wm2[k * 2 + o], p);
            logits[(long)node * 2 + o] = p;
        }
    }
}

extern "C" void kernel_launch(void* const* d_in, const int* in_sizes, int n_in,
                              void* d_out, int out_size, void* d_ws, size_t ws_size,
                              hipStream_t stream) {
    const float* x     = (const float*)d_in[0];
    const float* sim_x = (const float*)d_in[1];
    const int* src     = (const int*)d_in[2];
    const int* dst     = (const int*)d_in[3];
    const int* sim_src = (const int*)d_in[4];
    const int* sim_dst = (const int*)d_in[5];
    const float* W1_o = (const float*)d_in[6];
    const float* b1_o = (const float*)d_in[7];
    const float* W1_s = (const float*)d_in[8];
    const float* b1_s = (const float*)d_in[9];
    const float* Wm1  = (const float*)d_in[10];
    const float* bm1  = (const float*)d_in[11];
    const float* Wm2  = (const float*)d_in[12];
    const float* bm2  = (const float*)d_in[13];

    const int N  = in_sizes[0] / 128;  // 50000
    const int E  = in_sizes[2];        // 800000
    const int Es = in_sizes[4];
    const int NF = N * 64;
    const int B  = (N + 1023) >> 10;   // chunks per graph (49; must be <= 64)
    const int K  = (N + 31) >> 5;      // 32-node buckets per graph

    float* hall = (float*)d_out;                 // N x 384
    float* lgt  = hall + (long)N * 384;          // N x 2
    float* dinv = lgt;                           // [dinv_o N | dinv_s N] until MLP
    float* dinv_o = dinv;
    float* dinv_s = dinv + N;

    int* row_o  = (int*)d_ws;          // N+1
    int* row_s  = row_o + (N + 1);     // N+1
    int* cnt    = row_s + (N + 1);     // 2N
    int* esrc_o = cnt + 2 * N;         // E
    int* esrc_s = esrc_o + E;          // Es
    int* part   = esrc_s + Es;         // 2B
    int* bcur   = part + 2 * B;        // 2K
    __half* h16_o = (__half*)(bcur + 2 * K);     // N*64 halves each
    __half* h16_s = h16_o + (long)N * 64;
    __half* g16_o = h16_s + (long)N * 64;
    __half* g16_s = g16_o + (long)N * 64;
    size_t need_f16 = (size_t)((char*)(g16_s + (long)N * 64) - (char*)d_ws);
    bool f16path = ws_size >= need_f16;
    // staged[E+Es]: alias g16 when f16path (g16 written only in hop1, after
    // place consumed staged); otherwise place it right after bcur.
    int* staged = f16path ? (int*)g16_o : (int*)h16_o;

    int nb4  = (N + 3) / 4;
    int nb64 = (N + 63) / 64;
    int nfb  = (NF + 255) / 256;
    int ebA  = (E + Es + 255) / 256;

    // ---- CSR build ----
    hipMemsetAsync(cnt, 0, (size_t)(2 * N) * sizeof(int), stream);
    count2_kernel<<<ebA, 256, 0, stream>>>(dst, sim_dst, cnt, N, E, Es);
    scan_p1<<<2 * B, 256, 0, stream>>>(cnt, part, bcur, 2 * K, N, B);
    scan_p2<<<2, 64, 0, stream>>>(part, row_o, row_s, N, B);
    scan_p3<<<2 * B, 256, 0, stream>>>(cnt, part, row_o, row_s, dinv, N, B);
    bin2_kernel<<<ebA, 256, 0, stream>>>(src, dst, sim_src, sim_dst,
                                         row_o, row_s, bcur, staged, K, E, Es);
    place_kernel<<<2 * K, 256, 0, stream>>>(row_o, row_s, staged,
                                            esrc_o, esrc_s, N, K, E);

    // ---- input GEMMs: ortho -> slot 0, sim -> slot 192 (+ premul fp16 shadows) ----
    in_gemm_kernel<<<nb64, 256, 0, stream>>>(x, W1_o, b1_o, hall, 0,
                                             f16path ? h16_o : (__half*)nullptr, dinv_o, N);
    in_gemm_kernel<<<nb64, 256, 0, stream>>>(sim_x, W1_s, b1_s, hall, 192,
                                             f16path ? h16_s : (__half*)nullptr, dinv_s, N);

    if (f16path) {
        hop1_kernel<<<2 * nb4, 256, 0, stream>>>(row_o, esrc_o, dinv_o,
                                                 row_s, esrc_s, dinv_s,
                                                 h16_o, h16_s, g16_o, g16_s,
                                                 hall, N, nb4);
        hop2_kernel<<<2 * nb4, 256, 0, stream>>>(row_o, esrc_o, dinv_o,
                                                 row_s, esrc_s, dinv_s,
                                                 g16_o, g16_s, hall, N, nb4);
    } else {
        gather2_kernel<<<2 * nb4, 256, 0, stream>>>(row_o, esrc_o, dinv_o,
                                                    row_s, esrc_s, dinv_s,
                                                    hall, 0, 192, N, nb4);
        gather2_kernel<<<2 * nb4, 256, 0, stream>>>(row_o, esrc_o, dinv_o,
                                                    row_s, esrc_s, dinv_s,
                                                    hall, 64, 256, N, nb4);
        combine_kernel<<<nfb, 256, 0, stream>>>(hall, NF);
    }

    // ---- MLP head (overwrites dinv stash with logits) ----
    mlp_kernel<<<nb64, 256, 0, stream>>>(hall, Wm1, bm1, Wm2, bm2, lgt, N);
}

// Round 3
// 432.320 us; speedup vs baseline: 1.5809x; 1.5809x over previous
//
#include <hip/hip_runtime.h>
#include <hip/hip_fp16.h>

// 2-branch PolyConv GNN + MLP head. float32, int32 indices.
// f_k = L^k h, L(f) = f - dinv*S(f*dinv). Filters = linear combos of f_0,f_1,f_2:
//   ortho: o0 = 3f0-3f1+0.75f2, o1 = 3f1-1.5f2, o2 = 0.75f2
//   sim:   all three = 4(f0+f1+f2)
// R10 changes vs R9 (bin2 was 221us: sequential POSITIONS but random TIME/XCD ->
// line thrash persisted + 512-deep atomic contention on 1563 cursors):
//  CSR build replaced by two-level LDS radix partition -- every global write is
//  made by one block, contiguous, at one instant:
//   bhist:   per-graph 1024-node-bucket histogram (K=49<=64 -> one-wave scan).
//   bscan:   bucket bases -> brow, init global bucket cursors gcur.
//   partition: per 4096-edge block: LDS sort by bucket, ONE global atomicAdd
//     per (block,bucket) reserves a run, coalesced LDS->global stream of packed
//     (bk<<26)|(src<<10)|(d&1023).
//   place:   one 512-thr block per bucket: LDS per-node hist -> block scan ->
//     writes row+dinv (count2 + 3 scan kernels fused away), then scatters esrc
//     inside its private 64KB L2-resident window.
// hall slots (stride 384): ortho f0/f1/f2 -> 0/64/128, sim -> 192/256/320.
// dinv (2N f32) lives in logits region (overwritten by MLP last).
// d_ws: row_o[N+1] row_s[N+1] esrc_o[E] esrc_s[Es] bhist[128] brow[130] gcur[128]
//       h16_o[N*64] h16_s[N*64] g16_o[N*64] g16_s[N*64]  (halves)
//       staged[E+Es] aliases h16 (h16 written by in_gemm AFTER place consumed it).

#define KB_BITS 10          // 1024 nodes per bucket
#define KMAX 64             // max buckets per graph (N <= 65536)
#define PCHUNK 4096
#define PVPT 16

// Per-graph coarse-bucket histogram (both graphs, one launch).
__global__ __launch_bounds__(256) void bhist_kernel(
    const int* __restrict__ dst, const int* __restrict__ sim_dst,
    int* __restrict__ bhist, int E, int Es) {
    __shared__ int h[2 * KMAX];
    int tid = threadIdx.x;
    if (tid < 2 * KMAX) h[tid] = 0;
    __syncthreads();
    int total = E + Es;
    for (int e = blockIdx.x * 256 + tid; e < total; e += gridDim.x * 256) {
        if (e < E) atomicAdd(&h[dst[e] >> KB_BITS], 1);
        else       atomicAdd(&h[KMAX + (sim_dst[e - E] >> KB_BITS)], 1);
    }
    __syncthreads();
    if (tid < 2 * KMAX && h[tid]) atomicAdd(&bhist[tid], h[tid]);
}

// Bucket bases: brow[g][0..K] (exclusive prefix + total), gcur init = base.
// 128 threads = 2 waves, wave g scans graph g's KMAX bins.
__global__ __launch_bounds__(128) void bscan_kernel(
    const int* __restrict__ bhist, int* __restrict__ brow,
    int* __restrict__ gcur) {
    int g = threadIdx.x >> 6, lane = threadIdx.x & 63;
    int v = bhist[g * KMAX + lane];
    int inc = v;
    #pragma unroll
    for (int off = 1; off < 64; off <<= 1) {
        int u = __shfl_up(inc, off);
        if (lane >= off) inc += u;
    }
    int ex = inc - v;
    brow[g * (KMAX + 1) + lane] = ex;
    if (lane == 63) brow[g * (KMAX + 1) + KMAX] = inc;
    gcur[g * KMAX + lane] = ex;
}

// LDS radix partition: per 4096-edge block, sort by bucket in LDS, reserve one
// contiguous global run per bucket, stream out coalesced.
__global__ __launch_bounds__(256) void partition_kernel(
    const int* __restrict__ src, const int* __restrict__ dst,
    const int* __restrict__ sim_src, const int* __restrict__ sim_dst,
    int* __restrict__ gcur, unsigned* __restrict__ staged,
    int E, int Es, int nbo) {
    int b = blockIdx.x;
    const int* S; const int* D; int Eg; int goff; unsigned* stg;
    if (b < nbo) { S = src; D = dst; Eg = E; goff = 0; stg = staged; }
    else { b -= nbo; S = sim_src; D = sim_dst; Eg = Es; goff = KMAX; stg = staged + E; }
    int e0 = b * PCHUNK;
    int cnt_blk = Eg - e0; if (cnt_blk > PCHUNK) cnt_blk = PCHUNK;
    __shared__ int hist[KMAX], basep[KMAX], cur[KMAX], gbase[KMAX];
    __shared__ unsigned srt[PCHUNK];
    int tid = threadIdx.x;
    if (tid < KMAX) hist[tid] = 0;
    __syncthreads();
    unsigned full[PVPT];
    #pragma unroll
    for (int i = 0; i < PVPT; ++i) {
        int idx = i * 256 + tid;
        if (idx < cnt_blk) {
            int e = e0 + idx;
            int d = D[e];
            unsigned bk = (unsigned)d >> KB_BITS;
            full[i] = (bk << 26) | ((unsigned)S[e] << KB_BITS) |
                      (unsigned)(d & ((1 << KB_BITS) - 1));
            atomicAdd(&hist[bk], 1);
        } else full[i] = 0xFFFFFFFFu;   // impossible value (needs d >= 65535)
    }
    __syncthreads();
    if (tid < 64) {                      // wave 0: scan + global reservation
        int v = hist[tid];
        int inc = v;
        #pragma unroll
        for (int off = 1; off < 64; off <<= 1) {
            int u = __shfl_up(inc, off);
            if (tid >= off) inc += u;
        }
        int ex = inc - v;
        basep[tid] = ex;
        cur[tid] = ex;
        gbase[tid] = v ? atomicAdd(&gcur[goff + tid], v) : 0;
    }
    __syncthreads();
    #pragma unroll
    for (int i = 0; i < PVPT; ++i) {
        unsigned f = full[i];
        if (f != 0xFFFFFFFFu) {
            unsigned bk = f >> 26;
            int slot = atomicAdd(&cur[bk], 1);
            srt[slot] = f;
        }
    }
    __syncthreads();
    for (int slot = tid; slot < cnt_blk; slot += 256) {
        unsigned f = srt[slot];
        unsigned bk = f >> 26;
        int gpos = gbase[bk] + (slot - basep[bk]);
        stg[gpos] = f & 0x3FFFFFFu;      // (src<<10)|dlow
    }
}

// One block per bucket: per-node counts -> row+dinv (fuses count+scan), then
// scatter esrc inside the bucket's private window (L2-resident, line-merged).
__global__ __launch_bounds__(512) void place_kernel(
    const unsigned* __restrict__ staged, const int* __restrict__ brow,
    int* __restrict__ row_o, int* __restrict__ row_s,
    int* __restrict__ esrc_o, int* __restrict__ esrc_s,
    float* __restrict__ dinv, int N, int K, int E) {
    int b = blockIdx.x;
    const unsigned* stg; const int* br; int* row; int* esrc; float* dv;
    if (b < K) { stg = staged; br = brow; row = row_o; esrc = esrc_o; dv = dinv; }
    else { b -= K; stg = staged + E; br = brow + (KMAX + 1); row = row_s; esrc = esrc_s; dv = dinv + N; }
    int node0 = b << KB_BITS;
    int nn = N - node0; if (nn > (1 << KB_BITS)) nn = (1 << KB_BITS);
    int seg0 = br[b], seg1 = br[b + 1];
    __shared__ int ncnt[1 << KB_BITS];
    __shared__ int wsum[8];
    int tid = threadIdx.x;
    for (int i = tid; i < (1 << KB_BITS); i += 512) ncnt[i] = 0;
    __syncthreads();
    for (int j = seg0 + tid; j < seg1; j += 512)
        atomicAdd(&ncnt[stg[j] & ((1 << KB_BITS) - 1)], 1);
    __syncthreads();
    // block exclusive scan over ncnt[1024], 2 entries/thread
    int i0 = tid * 2;
    int v0 = ncnt[i0], v1 = ncnt[i0 + 1];
    int s = v0 + v1;
    int inc = s;
    #pragma unroll
    for (int off = 1; off < 64; off <<= 1) {
        int u = __shfl_up(inc, off);
        if ((tid & 63) >= off) inc += u;
    }
    if ((tid & 63) == 63) wsum[tid >> 6] = inc;
    __syncthreads();
    int wo = 0;
    for (int w = 0; w < (tid >> 6); ++w) wo += wsum[w];
    int ex = seg0 + wo + inc - s;        // global CSR offset of node node0+i0
    if (i0 < nn) {
        row[node0 + i0] = ex;
        dv[node0 + i0] = rsqrtf((float)(v0 > 1 ? v0 : 1));
    }
    if (i0 + 1 < nn) {
        row[node0 + i0 + 1] = ex + v0;
        dv[node0 + i0 + 1] = rsqrtf((float)(v1 > 1 ? v1 : 1));
    }
    if (b == K - 1 && tid == 0) row[N] = br[K];
    __syncthreads();                     // all scan reads of ncnt done
    ncnt[i0] = ex;                       // reuse as global-offset cursors
    ncnt[i0 + 1] = ex + v0;
    __syncthreads();
    for (int j = seg0 + tid; j < seg1; j += 512) {
        unsigned f = stg[j];
        int pos = atomicAdd(&ncnt[f & ((1 << KB_BITS) - 1)], 1);
        esrc[pos] = (int)(f >> KB_BITS);
    }
}

// Tiled: out[node*384+off+j] = relu(x[node,:]@W[:,j] + b[j]); K=128.
// Also writes fp16 shadow h16[node*64+j] = relu(...)*dinv[node] (premultiplied).
__global__ __launch_bounds__(256) void in_gemm_kernel(
    const float* __restrict__ x, const float* __restrict__ W,
    const float* __restrict__ b, float* __restrict__ out, int off,
    __half* __restrict__ h16, const float* __restrict__ dinvv, int n) {
    __shared__ float xs[64][132];
    __shared__ float Wf[128][68];
    int tid = threadIdx.x;
    int node0 = blockIdx.x * 64;
    const float4* wsrc = (const float4*)W;
    for (int i = tid; i < 2048; i += 256)
        *(float4*)&Wf[i >> 4][(i & 15) * 4] = wsrc[i];
    const float4* xsrc = (const float4*)x;
    for (int i = tid; i < 2048; i += 256) {
        int nl = i >> 5, c = i & 31;
        int node = node0 + nl;
        float4 v = make_float4(0.f, 0.f, 0.f, 0.f);
        if (node < n) v = xsrc[(long)node * 32 + c];
        *(float4*)&xs[nl][c * 4] = v;
    }
    __syncthreads();
    int tx = tid & 15, ty = tid >> 4;
    float acc[4][4] = {};
    #pragma unroll 2
    for (int k = 0; k < 128; k += 4) {
        float4 a[4], bb[4];
        #pragma unroll
        for (int i = 0; i < 4; ++i) a[i] = *(const float4*)&xs[ty * 4 + i][k];
        #pragma unroll
        for (int j = 0; j < 4; ++j) bb[j] = *(const float4*)&Wf[k + j][tx * 4];
        #pragma unroll
        for (int i = 0; i < 4; ++i) {
            acc[i][0] = fmaf(a[i].x, bb[0].x, acc[i][0]);
            acc[i][1] = fmaf(a[i].x, bb[0].y, acc[i][1]);
            acc[i][2] = fmaf(a[i].x, bb[0].z, acc[i][2]);
            acc[i][3] = fmaf(a[i].x, bb[0].w, acc[i][3]);
            acc[i][0] = fmaf(a[i].y, bb[1].x, acc[i][0]);
            acc[i][1] = fmaf(a[i].y, bb[1].y, acc[i][1]);
            acc[i][2] = fmaf(a[i].y, bb[1].z, acc[i][2]);
            acc[i][3] = fmaf(a[i].y, bb[1].w, acc[i][3]);
            acc[i][0] = fmaf(a[i].z, bb[2].x, acc[i][0]);
            acc[i][1] = fmaf(a[i].z, bb[2].y, acc[i][1]);
            acc[i][2] = fmaf(a[i].z, bb[2].z, acc[i][2]);
            acc[i][3] = fmaf(a[i].z, bb[2].w, acc[i][3]);
            acc[i][0] = fmaf(a[i].w, bb[3].x, acc[i][0]);
            acc[i][1] = fmaf(a[i].w, bb[3].y, acc[i][1]);
            acc[i][2] = fmaf(a[i].w, bb[3].z, acc[i][2]);
            acc[i][3] = fmaf(a[i].w, bb[3].w, acc[i][3]);
        }
    }
    float4 bias = *(const float4*)&b[tx * 4];
    #pragma unroll
    for (int i = 0; i < 4; ++i) {
        int node = node0 + ty * 4 + i;
        if (node >= n) break;
        float4 r;
        r.x = fmaxf(acc[i][0] + bias.x, 0.0f);
        r.y = fmaxf(acc[i][1] + bias.y, 0.0f);
        r.z = fmaxf(acc[i][2] + bias.z, 0.0f);
        r.w = fmaxf(acc[i][3] + bias.w, 0.0f);
        *(float4*)&out[(long)node * 384 + off + tx * 4] = r;
        if (h16) {
            float dvn = dinvv[node];
            __half hh[4];
            hh[0] = __float2half_rn(r.x * dvn);
            hh[1] = __float2half_rn(r.y * dvn);
            hh[2] = __float2half_rn(r.z * dvn);
            hh[3] = __float2half_rn(r.w * dvn);
            *(float2*)&h16[(long)node * 64 + tx * 4] = *(float2*)hh;
        }
    }
}

// Hop 1, both graphs merged. Gathers premultiplied fp16 h16 (= h*dinv), so the
// inner loop is a pure sum. Writes f1 fp32 -> hall base+64, f1*dinv fp16 -> g16.
__global__ __launch_bounds__(256) void hop1_kernel(
    const int* __restrict__ row_o, const int* __restrict__ esrc_o, const float* __restrict__ dinv_o,
    const int* __restrict__ row_s, const int* __restrict__ esrc_s, const float* __restrict__ dinv_s,
    const __half* __restrict__ h16_o, const __half* __restrict__ h16_s,
    __half* __restrict__ g16_o, __half* __restrict__ g16_s,
    float* __restrict__ hall, int n, int nb) {
    int b = blockIdx.x;
    const int* row; const int* esrc; const float* dinv; const __half* h16; __half* g16; int base;
    if (b < nb) { row = row_o; esrc = esrc_o; dinv = dinv_o; h16 = h16_o; g16 = g16_o; base = 0; }
    else { b -= nb; row = row_s; esrc = esrc_s; dinv = dinv_s; h16 = h16_s; g16 = g16_s; base = 192; }
    int d = b * 4 + (threadIdx.x >> 6);
    if (d >= n) return;
    int lane = threadIdx.x & 63;
    int p = row[d], end = row[d + 1];
    long ob = (long)d * 384 + lane;
    float dd = dinv[d];
    float f0 = hall[ob + base];
    float a0 = 0.f, a1 = 0.f, a2 = 0.f, a3 = 0.f;
    for (; p + 8 <= end; p += 8) {
        int s0 = esrc[p], s1 = esrc[p + 1], s2 = esrc[p + 2], s3 = esrc[p + 3];
        int s4 = esrc[p + 4], s5 = esrc[p + 5], s6 = esrc[p + 6], s7 = esrc[p + 7];
        a0 += __half2float(h16[(long)s0 * 64 + lane]);
        a1 += __half2float(h16[(long)s1 * 64 + lane]);
        a2 += __half2float(h16[(long)s2 * 64 + lane]);
        a3 += __half2float(h16[(long)s3 * 64 + lane]);
        a0 += __half2float(h16[(long)s4 * 64 + lane]);
        a1 += __half2float(h16[(long)s5 * 64 + lane]);
        a2 += __half2float(h16[(long)s6 * 64 + lane]);
        a3 += __half2float(h16[(long)s7 * 64 + lane]);
    }
    for (; p < end; ++p) {
        int s = esrc[p];
        a0 += __half2float(h16[(long)s * 64 + lane]);
    }
    float acc = (a0 + a1) + (a2 + a3);
    float f1 = f0 - acc * dd;
    hall[ob + base + 64] = f1;
    g16[(long)d * 64 + lane] = __float2half_rn(f1 * dd);
}

// Hop 2 + fused theta-combine. Gathers premultiplied fp16 g16 (in ws), so every
// hall row is touched only by its own wave -> race-free overwrite.
__global__ __launch_bounds__(256) void hop2_kernel(
    const int* __restrict__ row_o, const int* __restrict__ esrc_o, const float* __restrict__ dinv_o,
    const int* __restrict__ row_s, const int* __restrict__ esrc_s, const float* __restrict__ dinv_s,
    const __half* __restrict__ g16_o, const __half* __restrict__ g16_s,
    float* __restrict__ hall, int n, int nb) {
    int b = blockIdx.x;
    bool ortho = b < nb;
    const int* row; const int* esrc; const float* dinv; const __half* g16; int base;
    if (ortho) { row = row_o; esrc = esrc_o; dinv = dinv_o; g16 = g16_o; base = 0; }
    else { b -= nb; row = row_s; esrc = esrc_s; dinv = dinv_s; g16 = g16_s; base = 192; }
    int d = b * 4 + (threadIdx.x >> 6);
    if (d >= n) return;
    int lane = threadIdx.x & 63;
    int p = row[d], end = row[d + 1];
    long ob = (long)d * 384 + lane;
    float dd = dinv[d];
    float f0 = hall[ob + base];
    float f1 = hall[ob + base + 64];
    float a0 = 0.f, a1 = 0.f, a2 = 0.f, a3 = 0.f;
    for (; p + 8 <= end; p += 8) {
        int s0 = esrc[p], s1 = esrc[p + 1], s2 = esrc[p + 2], s3 = esrc[p + 3];
        int s4 = esrc[p + 4], s5 = esrc[p + 5], s6 = esrc[p + 6], s7 = esrc[p + 7];
        a0 += __half2float(g16[(long)s0 * 64 + lane]);
        a1 += __half2float(g16[(long)s1 * 64 + lane]);
        a2 += __half2float(g16[(long)s2 * 64 + lane]);
        a3 += __half2float(g16[(long)s3 * 64 + lane]);
        a0 += __half2float(g16[(long)s4 * 64 + lane]);
        a1 += __half2float(g16[(long)s5 * 64 + lane]);
        a2 += __half2float(g16[(long)s6 * 64 + lane]);
        a3 += __half2float(g16[(long)s7 * 64 + lane]);
    }
    for (; p < end; ++p) {
        int s = esrc[p];
        a0 += __half2float(g16[(long)s * 64 + lane]);
    }
    float acc = (a0 + a1) + (a2 + a3);
    float f2 = f1 - acc * dd;
    if (ortho) {
        hall[ob]       = 3.0f * f0 - 3.0f * f1 + 0.75f * f2;
        hall[ob + 64]  = 3.0f * f1 - 1.5f * f2;
        hall[ob + 128] = 0.75f * f2;
    } else {
        float ss = 4.0f * (f0 + f1 + f2);
        hall[ob + 192] = ss; hall[ob + 256] = ss; hall[ob + 320] = ss;
    }
}

// ---------- fallback path (ws too small for fp16 shadows) ----------
__global__ __launch_bounds__(256) void gather2_kernel(
    const int* __restrict__ row_o, const int* __restrict__ esrc_o, const float* __restrict__ dinv_o,
    const int* __restrict__ row_s, const int* __restrict__ esrc_s, const float* __restrict__ dinv_s,
    float* __restrict__ hall, int in_off_o, int in_off_s, int n, int nb) {
    int b = blockIdx.x;
    const int* row; const int* esrc; const float* dinv; int in_off;
    if (b < nb) { row = row_o; esrc = esrc_o; dinv = dinv_o; in_off = in_off_o; }
    else { b -= nb; row = row_s; esrc = esrc_s; dinv = dinv_s; in_off = in_off_s; }
    int d = b * 4 + (threadIdx.x >> 6);
    if (d >= n) return;
    int lane = threadIdx.x & 63;
    int p = row[d], end = row[d + 1];
    const float* fin = hall + in_off;
    float a0 = 0.f, a1 = 0.f, a2 = 0.f, a3 = 0.f;
    for (; p + 4 <= end; p += 4) {
        int s0 = esrc[p], s1 = esrc[p + 1], s2 = esrc[p + 2], s3 = esrc[p + 3];
        a0 = fmaf(fin[(long)s0 * 384 + lane], dinv[s0], a0);
        a1 = fmaf(fin[(long)s1 * 384 + lane], dinv[s1], a1);
        a2 = fmaf(fin[(long)s2 * 384 + lane], dinv[s2], a2);
        a3 = fmaf(fin[(long)s3 * 384 + lane], dinv[s3], a3);
    }
    for (; p < end; ++p) {
        int s = esrc[p];
        a0 = fmaf(fin[(long)s * 384 + lane], dinv[s], a0);
    }
    float acc = (a0 + a1) + (a2 + a3);
    long ob = (long)d * 384 + lane;
    hall[ob + in_off + 64] = fin[ob] - acc * dinv[d];
}

__global__ __launch_bounds__(256) void combine_kernel(float* __restrict__ h, int nf) {
    int i = blockIdx.x * 256 + threadIdx.x;
    if (i >= nf) return;
    long ob = (long)(i >> 6) * 384 + (i & 63);
    float f0v = h[ob], f1v = h[ob + 64], f2v = h[ob + 128];
    h[ob]       = 3.0f * f0v - 3.0f * f1v + 0.75f * f2v;
    h[ob + 64]  = 3.0f * f1v - 1.5f * f2v;
    h[ob + 128] = 0.75f * f2v;
    float ss = 4.0f * (h[ob + 192] + h[ob + 256] + h[ob + 320]);
    h[ob + 192] = ss; h[ob + 256] = ss; h[ob + 320] = ss;
}
// -------------------------------------------------------------------

// logits = relu(h_all @ Wm1 + bm1) @ Wm2 + bm2. Tiled, K=384 in 3 chunks.
__global__ __launch_bounds__(256) void mlp_kernel(
    const float* __restrict__ hall, const float* __restrict__ Wm1,
    const float* __restrict__ bm1, const float* __restrict__ Wm2,
    const float* __restrict__ bm2, float* __restrict__ logits, int n) {
    __shared__ float xs[64][132];
    __shared__ float Wf[128][68];
    int tid = threadIdx.x;
    int node0 = blockIdx.x * 64;
    int tx = tid & 15, ty = tid >> 4;
    float acc[4][4] = {};
    const float4* wsrc = (const float4*)Wm1;
    const float4* hsrc = (const float4*)hall;
    for (int c = 0; c < 3; ++c) {
        __syncthreads();
        for (int i = tid; i < 2048; i += 256)
            *(float4*)&Wf[i >> 4][(i & 15) * 4] = wsrc[c * 2048 + i];
        for (int i = tid; i < 2048; i += 256) {
            int nl = i >> 5, cc = i & 31;
            int node = node0 + nl;
            float4 v = make_float4(0.f, 0.f, 0.f, 0.f);
            if (node < n) v = hsrc[(long)node * 96 + c * 32 + cc];
            *(float4*)&xs[nl][cc * 4] = v;
        }
        __syncthreads();
        #pragma unroll 2
        for (int k = 0; k < 128; k += 4) {
            float4 a[4], bb[4];
            #pragma unroll
            for (int i = 0; i < 4; ++i) a[i] = *(const float4*)&xs[ty * 4 + i][k];
            #pragma unroll
            for (int j = 0; j < 4; ++j) bb[j] = *(const float4*)&Wf[k + j][tx * 4];
            #pragma unroll
            for (int i = 0; i < 4; ++i) {
                acc[i][0] = fmaf(a[i].x, bb[0].x, acc[i][0]);
                acc[i][1] = fmaf(a[i].x, bb[0].y, acc[i][1]);
                acc[i][2] = fmaf(a[i].x, bb[0].z, acc[i][2]);
                acc[i][3] = fmaf(a[i].x, bb[0].w, acc[i][3]);
                acc[i][0] = fmaf(a[i].y, bb[1].x, acc[i][0]);
                acc[i][1] = fmaf(a[i].y, bb[1].y, acc[i][1]);
                acc[i][2] = fmaf(a[i].y, bb[1].z, acc[i][2]);
                acc[i][3] = fmaf(a[i].y, bb[1].w, acc[i][3]);
                acc[i][0] = fmaf(a[i].z, bb[2].x, acc[i][0]);
                acc[i][1] = fmaf(a[i].z, bb[2].y, acc[i][1]);
                acc[i][2] = fmaf(a[i].z, bb[2].z, acc[i][2]);
                acc[i][3] = fmaf(a[i].z, bb[2].w, acc[i][3]);
                acc[i][0] = fmaf(a[i].w, bb[3].x, acc[i][0]);
                acc[i][1] = fmaf(a[i].w, bb[3].y, acc[i][1]);
                acc[i][2] = fmaf(a[i].w, bb[3].z, acc[i][2]);
                acc[i][3] = fmaf(a[i].w, bb[3].w, acc[i][3]);
            }
        }
    }
    __syncthreads();
    float4 bias = *(const float4*)&bm1[tx * 4];
    #pragma unroll
    for (int i = 0; i < 4; ++i) {
        xs[ty * 4 + i][tx * 4 + 0] = fmaxf(acc[i][0] + bias.x, 0.0f);
        xs[ty * 4 + i][tx * 4 + 1] = fmaxf(acc[i][1] + bias.y, 0.0f);
        xs[ty * 4 + i][tx * 4 + 2] = fmaxf(acc[i][2] + bias.z, 0.0f);
        xs[ty * 4 + i][tx * 4 + 3] = fmaxf(acc[i][3] + bias.w, 0.0f);
    }
    __syncthreads();
    if (tid < 128) {
        int nl = tid >> 1, o = tid & 1;
        int node = node0 + nl;
        if (node < n) {
            float p = bm2[o];
            #pragma unroll 8
            for (int k = 0; k < 64; ++k) p = fmaf(xs[nl][k], Wm2[k * 2 + o], p);
            logits[(long)node * 2 + o] = p;
        }
    }
}

extern "C" void kernel_launch(void* const* d_in, const int* in_sizes, int n_in,
                              void* d_out, int out_size, void* d_ws, size_t ws_size,
                              hipStream_t stream) {
    const float* x     = (const float*)d_in[0];
    const float* sim_x = (const float*)d_in[1];
    const int* src     = (const int*)d_in[2];
    const int* dst     = (const int*)d_in[3];
    const int* sim_src = (const int*)d_in[4];
    const int* sim_dst = (const int*)d_in[5];
    const float* W1_o = (const float*)d_in[6];
    const float* b1_o = (const float*)d_in[7];
    const float* W1_s = (const float*)d_in[8];
    const float* b1_s = (const float*)d_in[9];
    const float* Wm1  = (const float*)d_in[10];
    const float* bm1  = (const float*)d_in[11];
    const float* Wm2  = (const float*)d_in[12];
    const float* bm2  = (const float*)d_in[13];

    const int N  = in_sizes[0] / 128;  // 50000
    const int E  = in_sizes[2];        // 800000
    const int Es = in_sizes[4];
    const int NF = N * 64;
    const int K  = (N + (1 << KB_BITS) - 1) >> KB_BITS;  // 1024-node buckets (<=64)

    float* hall = (float*)d_out;                 // N x 384
    float* lgt  = hall + (long)N * 384;          // N x 2
    float* dinv = lgt;                           // [dinv_o N | dinv_s N] until MLP
    float* dinv_o = dinv;
    float* dinv_s = dinv + N;

    int* row_o  = (int*)d_ws;            // N+1
    int* row_s  = row_o + (N + 1);       // N+1
    int* esrc_o = row_s + (N + 1);       // E
    int* esrc_s = esrc_o + E;            // Es
    int* bhist  = esrc_s + Es;           // 2*KMAX
    int* brow   = bhist + 2 * KMAX;      // 2*(KMAX+1)
    int* gcur   = brow + 2 * (KMAX + 1); // 2*KMAX
    __half* h16_o = (__half*)(gcur + 2 * KMAX);  // N*64 halves each
    __half* h16_s = h16_o + (long)N * 64;
    __half* g16_o = h16_s + (long)N * 64;
    __half* g16_s = g16_o + (long)N * 64;
    size_t need_f16 = (size_t)((char*)(g16_s + (long)N * 64) - (char*)d_ws);
    bool f16path = ws_size >= need_f16;
    // staged[E+Es] aliases h16 region: consumed by place BEFORE in_gemm writes h16.
    unsigned* staged = (unsigned*)h16_o;

    int nb4  = (N + 3) / 4;
    int nb64 = (N + 63) / 64;
    int nfb  = (NF + 255) / 256;
    int nbo  = (E + PCHUNK - 1) / PCHUNK;
    int nbs  = (Es + PCHUNK - 1) / PCHUNK;

    // ---- CSR build: hist -> bases -> LDS radix partition -> per-bucket place ----
    hipMemsetAsync(bhist, 0, (size_t)(2 * KMAX) * sizeof(int), stream);
    bhist_kernel<<<256, 256, 0, stream>>>(dst, sim_dst, bhist, E, Es);
    bscan_kernel<<<1, 128, 0, stream>>>(bhist, brow, gcur);
    partition_kernel<<<nbo + nbs, 256, 0, stream>>>(src, dst, sim_src, sim_dst,
                                                    gcur, staged, E, Es, nbo);
    place_kernel<<<2 * K, 512, 0, stream>>>(staged, brow, row_o, row_s,
                                            esrc_o, esrc_s, dinv, N, K, E);

    // ---- input GEMMs: ortho -> slot 0, sim -> slot 192 (+ premul fp16 shadows) ----
    in_gemm_kernel<<<nb64, 256, 0, stream>>>(x, W1_o, b1_o, hall, 0,
                                             f16path ? h16_o : (__half*)nullptr, dinv_o, N);
    in_gemm_kernel<<<nb64, 256, 0, stream>>>(sim_x, W1_s, b1_s, hall, 192,
                                             f16path ? h16_s : (__half*)nullptr, dinv_s, N);

    if (f16path) {
        hop1_kernel<<<2 * nb4, 256, 0, stream>>>(row_o, esrc_o, dinv_o,
                                                 row_s, esrc_s, dinv_s,
                                                 h16_o, h16_s, g16_o, g16_s,
                                                 hall, N, nb4);
        hop2_kernel<<<2 * nb4, 256, 0, stream>>>(row_o, esrc_o, dinv_o,
                                                 row_s, esrc_s, dinv_s,
                                                 g16_o, g16_s, hall, N, nb4);
    } else {
        gather2_kernel<<<2 * nb4, 256, 0, stream>>>(row_o, esrc_o, dinv_o,
                                                    row_s, esrc_s, dinv_s,
                                                    hall, 0, 192, N, nb4);
        gather2_kernel<<<2 * nb4, 256, 0, stream>>>(row_o, esrc_o, dinv_o,
                                                    row_s, esrc_s, dinv_s,
                                                    hall, 64, 256, N, nb4);
        combine_kernel<<<nfb, 256, 0, stream>>>(hall, NF);
    }

    // ---- MLP head (overwrites dinv stash with logits) ----
    mlp_kernel<<<nb64, 256, 0, stream>>>(hall, Wm1, bm1, Wm2, bm2, lgt, N);
}

// Round 4
// 411.837 us; speedup vs baseline: 1.6595x; 1.0497x over previous
//
#include <hip/hip_runtime.h>
#include <hip/hip_fp16.h>

// 2-branch PolyConv GNN + MLP head. float32, int32 indices.
// f_k = L^k h, L(f) = f - dinv*S(f*dinv). Filters = linear combos of f_0,f_1,f_2:
//   ortho: o0 = 3f0-3f1+0.75f2, o1 = 3f1-1.5f2, o2 = 0.75f2
//   sim:   all three = 4(f0+f1+f2)
// R11 changes vs R10 (hop2 71.7us: 51MB of fp32 f0/f1 re-reads + 8xXCD gather
// L2-fill amplification were the remaining fat):
//  (1) all-fp16 intermediates: in_gemm writes ONLY h16 (=relu*dinv, no fp32
//      hall); hop1 pure fp16 (g16 = h16_own - acc*dd^2); hop2 reconstructs
//      f0,f1 from own fp16 rows via sqrt(deg) and writes the only fp32 data:
//      the final hall output. Cuts ~128MB of fp32 intermediate traffic.
//  (2) XCD-dedicated hops: graph o -> XCD slots 0-3, graph s -> 4-7 (blockIdx&7
//      decode; round-robin dispatch assumption -- worst case neutral). Halves
//      per-graph gather L2 fill (8 XCDs -> 4).
//  (3) MLP sim-fold: sim's 3 output slots are identical -> fold Wm1 rows
//      192..383 into 64 (exact fp32 add) -> mlp K=384->256, -25.6MB fetch.
// hall slots (stride 384): ortho f0/f1/f2 -> 0/64/128, sim -> 192/256/320.
// dinv (2N f32) lives in logits region (overwritten by MLP last).
// d_ws: row_o[N+1] row_s[N+1] esrc_o[E] esrc_s[Es] bhist[128] brow[130] gcur[128]
//       w1f[256*64 f32] h16_o[N*64] h16_s[N*64] g16_o[N*64] g16_s[N*64] (halves)
//       staged[E+Es] aliases h16 (consumed by place BEFORE in_gemm writes h16).

#define KB_BITS 10          // 1024 nodes per bucket
#define KMAX 64             // max buckets per graph (N <= 65536)
#define PCHUNK 4096
#define PVPT 16

// Per-graph coarse-bucket histogram (both graphs, one launch).
__global__ __launch_bounds__(256) void bhist_kernel(
    const int* __restrict__ dst, const int* __restrict__ sim_dst,
    int* __restrict__ bhist, int E, int Es) {
    __shared__ int h[2 * KMAX];
    int tid = threadIdx.x;
    if (tid < 2 * KMAX) h[tid] = 0;
    __syncthreads();
    int total = E + Es;
    for (int e = blockIdx.x * 256 + tid; e < total; e += gridDim.x * 256) {
        if (e < E) atomicAdd(&h[dst[e] >> KB_BITS], 1);
        else       atomicAdd(&h[KMAX + (sim_dst[e - E] >> KB_BITS)], 1);
    }
    __syncthreads();
    if (tid < 2 * KMAX && h[tid]) atomicAdd(&bhist[tid], h[tid]);
}

// Bucket bases: brow[g][0..K] (exclusive prefix + total), gcur init = base.
__global__ __launch_bounds__(128) void bscan_kernel(
    const int* __restrict__ bhist, int* __restrict__ brow,
    int* __restrict__ gcur) {
    int g = threadIdx.x >> 6, lane = threadIdx.x & 63;
    int v = bhist[g * KMAX + lane];
    int inc = v;
    #pragma unroll
    for (int off = 1; off < 64; off <<= 1) {
        int u = __shfl_up(inc, off);
        if (lane >= off) inc += u;
    }
    int ex = inc - v;
    brow[g * (KMAX + 1) + lane] = ex;
    if (lane == 63) brow[g * (KMAX + 1) + KMAX] = inc;
    gcur[g * KMAX + lane] = ex;
}

// LDS radix partition: per 4096-edge block, sort by bucket in LDS, reserve one
// contiguous global run per bucket, stream out coalesced.
__global__ __launch_bounds__(256) void partition_kernel(
    const int* __restrict__ src, const int* __restrict__ dst,
    const int* __restrict__ sim_src, const int* __restrict__ sim_dst,
    int* __restrict__ gcur, unsigned* __restrict__ staged,
    int E, int Es, int nbo) {
    int b = blockIdx.x;
    const int* S; const int* D; int Eg; int goff; unsigned* stg;
    if (b < nbo) { S = src; D = dst; Eg = E; goff = 0; stg = staged; }
    else { b -= nbo; S = sim_src; D = sim_dst; Eg = Es; goff = KMAX; stg = staged + E; }
    int e0 = b * PCHUNK;
    int cnt_blk = Eg - e0; if (cnt_blk > PCHUNK) cnt_blk = PCHUNK;
    __shared__ int hist[KMAX], basep[KMAX], cur[KMAX], gbase[KMAX];
    __shared__ unsigned srt[PCHUNK];
    int tid = threadIdx.x;
    if (tid < KMAX) hist[tid] = 0;
    __syncthreads();
    unsigned full[PVPT];
    #pragma unroll
    for (int i = 0; i < PVPT; ++i) {
        int idx = i * 256 + tid;
        if (idx < cnt_blk) {
            int e = e0 + idx;
            int d = D[e];
            unsigned bk = (unsigned)d >> KB_BITS;
            full[i] = (bk << 26) | ((unsigned)S[e] << KB_BITS) |
                      (unsigned)(d & ((1 << KB_BITS) - 1));
            atomicAdd(&hist[bk], 1);
        } else full[i] = 0xFFFFFFFFu;
    }
    __syncthreads();
    if (tid < 64) {
        int v = hist[tid];
        int inc = v;
        #pragma unroll
        for (int off = 1; off < 64; off <<= 1) {
            int u = __shfl_up(inc, off);
            if (tid >= off) inc += u;
        }
        int ex = inc - v;
        basep[tid] = ex;
        cur[tid] = ex;
        gbase[tid] = v ? atomicAdd(&gcur[goff + tid], v) : 0;
    }
    __syncthreads();
    #pragma unroll
    for (int i = 0; i < PVPT; ++i) {
        unsigned f = full[i];
        if (f != 0xFFFFFFFFu) {
            unsigned bk = f >> 26;
            int slot = atomicAdd(&cur[bk], 1);
            srt[slot] = f;
        }
    }
    __syncthreads();
    for (int slot = tid; slot < cnt_blk; slot += 256) {
        unsigned f = srt[slot];
        unsigned bk = f >> 26;
        int gpos = gbase[bk] + (slot - basep[bk]);
        stg[gpos] = f & 0x3FFFFFFu;      // (src<<10)|dlow
    }
}

// One block per bucket: per-node counts -> row+dinv (fuses count+scan), then
// scatter esrc inside the bucket's private window (L2-resident, line-merged).
__global__ __launch_bounds__(512) void place_kernel(
    const unsigned* __restrict__ staged, const int* __restrict__ brow,
    int* __restrict__ row_o, int* __restrict__ row_s,
    int* __restrict__ esrc_o, int* __restrict__ esrc_s,
    float* __restrict__ dinv, int N, int K, int E) {
    int b = blockIdx.x;
    const unsigned* stg; const int* br; int* row; int* esrc; float* dv;
    if (b < K) { stg = staged; br = brow; row = row_o; esrc = esrc_o; dv = dinv; }
    else { b -= K; stg = staged + E; br = brow + (KMAX + 1); row = row_s; esrc = esrc_s; dv = dinv + N; }
    int node0 = b << KB_BITS;
    int nn = N - node0; if (nn > (1 << KB_BITS)) nn = (1 << KB_BITS);
    int seg0 = br[b], seg1 = br[b + 1];
    __shared__ int ncnt[1 << KB_BITS];
    __shared__ int wsum[8];
    int tid = threadIdx.x;
    for (int i = tid; i < (1 << KB_BITS); i += 512) ncnt[i] = 0;
    __syncthreads();
    for (int j = seg0 + tid; j < seg1; j += 512)
        atomicAdd(&ncnt[stg[j] & ((1 << KB_BITS) - 1)], 1);
    __syncthreads();
    int i0 = tid * 2;
    int v0 = ncnt[i0], v1 = ncnt[i0 + 1];
    int s = v0 + v1;
    int inc = s;
    #pragma unroll
    for (int off = 1; off < 64; off <<= 1) {
        int u = __shfl_up(inc, off);
        if ((tid & 63) >= off) inc += u;
    }
    if ((tid & 63) == 63) wsum[tid >> 6] = inc;
    __syncthreads();
    int wo = 0;
    for (int w = 0; w < (tid >> 6); ++w) wo += wsum[w];
    int ex = seg0 + wo + inc - s;
    if (i0 < nn) {
        row[node0 + i0] = ex;
        dv[node0 + i0] = rsqrtf((float)(v0 > 1 ? v0 : 1));
    }
    if (i0 + 1 < nn) {
        row[node0 + i0 + 1] = ex + v0;
        dv[node0 + i0 + 1] = rsqrtf((float)(v1 > 1 ? v1 : 1));
    }
    if (b == K - 1 && tid == 0) row[N] = br[K];
    __syncthreads();
    ncnt[i0] = ex;
    ncnt[i0 + 1] = ex + v0;
    __syncthreads();
    for (int j = seg0 + tid; j < seg1; j += 512) {
        unsigned f = stg[j];
        int pos = atomicAdd(&ncnt[f & ((1 << KB_BITS) - 1)], 1);
        esrc[pos] = (int)(f >> KB_BITS);
    }
}

// Fold Wm1 (384x64) -> w1f (256x64): rows 192..255 = sum of the 3 sim blocks.
__global__ __launch_bounds__(256) void fold_kernel(
    const float* __restrict__ Wm1, float* __restrict__ w1f) {
    int i = blockIdx.x * 256 + threadIdx.x;
    if (i >= 256 * 64) return;
    int k = i >> 6, j = i & 63;
    float v = Wm1[k * 64 + j];
    if (k >= 192) v += Wm1[(k + 64) * 64 + j] + Wm1[(k + 128) * 64 + j];
    w1f[i] = v;
}

// Tiled GEMM: relu(x@W+b). f16path: writes ONLY h16 = relu*dinv (premul).
// Fallback: writes fp32 hall slot.
__global__ __launch_bounds__(256) void in_gemm_kernel(
    const float* __restrict__ x, const float* __restrict__ W,
    const float* __restrict__ b, float* __restrict__ out, int off,
    __half* __restrict__ h16, const float* __restrict__ dinvv, int n) {
    __shared__ float xs[64][132];
    __shared__ float Wf[128][68];
    int tid = threadIdx.x;
    int node0 = blockIdx.x * 64;
    const float4* wsrc = (const float4*)W;
    for (int i = tid; i < 2048; i += 256)
        *(float4*)&Wf[i >> 4][(i & 15) * 4] = wsrc[i];
    const float4* xsrc = (const float4*)x;
    for (int i = tid; i < 2048; i += 256) {
        int nl = i >> 5, c = i & 31;
        int node = node0 + nl;
        float4 v = make_float4(0.f, 0.f, 0.f, 0.f);
        if (node < n) v = xsrc[(long)node * 32 + c];
        *(float4*)&xs[nl][c * 4] = v;
    }
    __syncthreads();
    int tx = tid & 15, ty = tid >> 4;
    float acc[4][4] = {};
    #pragma unroll 2
    for (int k = 0; k < 128; k += 4) {
        float4 a[4], bb[4];
        #pragma unroll
        for (int i = 0; i < 4; ++i) a[i] = *(const float4*)&xs[ty * 4 + i][k];
        #pragma unroll
        for (int j = 0; j < 4; ++j) bb[j] = *(const float4*)&Wf[k + j][tx * 4];
        #pragma unroll
        for (int i = 0; i < 4; ++i) {
            acc[i][0] = fmaf(a[i].x, bb[0].x, acc[i][0]);
            acc[i][1] = fmaf(a[i].x, bb[0].y, acc[i][1]);
            acc[i][2] = fmaf(a[i].x, bb[0].z, acc[i][2]);
            acc[i][3] = fmaf(a[i].x, bb[0].w, acc[i][3]);
            acc[i][0] = fmaf(a[i].y, bb[1].x, acc[i][0]);
            acc[i][1] = fmaf(a[i].y, bb[1].y, acc[i][1]);
            acc[i][2] = fmaf(a[i].y, bb[1].z, acc[i][2]);
            acc[i][3] = fmaf(a[i].y, bb[1].w, acc[i][3]);
            acc[i][0] = fmaf(a[i].z, bb[2].x, acc[i][0]);
            acc[i][1] = fmaf(a[i].z, bb[2].y, acc[i][1]);
            acc[i][2] = fmaf(a[i].z, bb[2].z, acc[i][2]);
            acc[i][3] = fmaf(a[i].z, bb[2].w, acc[i][3]);
            acc[i][0] = fmaf(a[i].w, bb[3].x, acc[i][0]);
            acc[i][1] = fmaf(a[i].w, bb[3].y, acc[i][1]);
            acc[i][2] = fmaf(a[i].w, bb[3].z, acc[i][2]);
            acc[i][3] = fmaf(a[i].w, bb[3].w, acc[i][3]);
        }
    }
    float4 bias = *(const float4*)&b[tx * 4];
    #pragma unroll
    for (int i = 0; i < 4; ++i) {
        int node = node0 + ty * 4 + i;
        if (node >= n) break;
        float4 r;
        r.x = fmaxf(acc[i][0] + bias.x, 0.0f);
        r.y = fmaxf(acc[i][1] + bias.y, 0.0f);
        r.z = fmaxf(acc[i][2] + bias.z, 0.0f);
        r.w = fmaxf(acc[i][3] + bias.w, 0.0f);
        if (out) *(float4*)&out[(long)node * 384 + off + tx * 4] = r;
        if (h16) {
            float dvn = dinvv[node];
            __half hh[4];
            hh[0] = __float2half_rn(r.x * dvn);
            hh[1] = __float2half_rn(r.y * dvn);
            hh[2] = __float2half_rn(r.z * dvn);
            hh[3] = __float2half_rn(r.w * dvn);
            *(float2*)&h16[(long)node * 64 + tx * 4] = *(float2*)hh;
        }
    }
}

// Hop 1, pure fp16: g16 = h16_own - acc*dd^2 (= f1*dinv). No fp32 traffic.
// XCD-dedicated: graph o on XCD slots 0-3, graph s on 4-7 (blockIdx&7).
__global__ __launch_bounds__(256) void hop1_kernel(
    const int* __restrict__ row_o, const int* __restrict__ esrc_o,
    const int* __restrict__ row_s, const int* __restrict__ esrc_s,
    const __half* __restrict__ h16_o, const __half* __restrict__ h16_s,
    __half* __restrict__ g16_o, __half* __restrict__ g16_s,
    int n, int nb4) {
    int slot = blockIdx.x & 7;
    int g = slot >> 2;
    int bl = (blockIdx.x >> 3) * 4 + (slot & 3);
    if (bl >= nb4) return;
    const int* row; const int* esrc; const __half* h16; __half* g16;
    if (g == 0) { row = row_o; esrc = esrc_o; h16 = h16_o; g16 = g16_o; }
    else { row = row_s; esrc = esrc_s; h16 = h16_s; g16 = g16_s; }
    int d = bl * 4 + (threadIdx.x >> 6);
    if (d >= n) return;
    int lane = threadIdx.x & 63;
    int p = row[d], end = row[d + 1];
    int deg = end - p;
    float degf = (float)(deg > 1 ? deg : 1);
    float dd = rsqrtf(degf);
    float h16v = __half2float(h16[(long)d * 64 + lane]);
    float a0 = 0.f, a1 = 0.f, a2 = 0.f, a3 = 0.f;
    for (; p + 8 <= end; p += 8) {
        int s0 = esrc[p], s1 = esrc[p + 1], s2 = esrc[p + 2], s3 = esrc[p + 3];
        int s4 = esrc[p + 4], s5 = esrc[p + 5], s6 = esrc[p + 6], s7 = esrc[p + 7];
        a0 += __half2float(h16[(long)s0 * 64 + lane]);
        a1 += __half2float(h16[(long)s1 * 64 + lane]);
        a2 += __half2float(h16[(long)s2 * 64 + lane]);
        a3 += __half2float(h16[(long)s3 * 64 + lane]);
        a0 += __half2float(h16[(long)s4 * 64 + lane]);
        a1 += __half2float(h16[(long)s5 * 64 + lane]);
        a2 += __half2float(h16[(long)s6 * 64 + lane]);
        a3 += __half2float(h16[(long)s7 * 64 + lane]);
    }
    for (; p < end; ++p) {
        int s = esrc[p];
        a0 += __half2float(h16[(long)s * 64 + lane]);
    }
    float acc = (a0 + a1) + (a2 + a3);
    // g16 = f1*dinv = f0*dd - acc*dd^2 = h16v - acc*dd^2
    g16[(long)d * 64 + lane] = __float2half_rn(h16v - acc * dd * dd);
}

// Hop 2 + theta-combine: reconstruct f0,f1 from own fp16 rows (sqrt(deg)),
// gather g16, write the final fp32 hall slots (the only fp32 data).
__global__ __launch_bounds__(256) void hop2_kernel(
    const int* __restrict__ row_o, const int* __restrict__ esrc_o,
    const int* __restrict__ row_s, const int* __restrict__ esrc_s,
    const __half* __restrict__ h16_o, const __half* __restrict__ h16_s,
    const __half* __restrict__ g16_o, const __half* __restrict__ g16_s,
    float* __restrict__ hall, int n, int nb4) {
    int slot = blockIdx.x & 7;
    int g = slot >> 2;
    int bl = (blockIdx.x >> 3) * 4 + (slot & 3);
    if (bl >= nb4) return;
    const int* row; const int* esrc; const __half* h16; const __half* g16; int base;
    if (g == 0) { row = row_o; esrc = esrc_o; h16 = h16_o; g16 = g16_o; base = 0; }
    else { row = row_s; esrc = esrc_s; h16 = h16_s; g16 = g16_s; base = 192; }
    int d = bl * 4 + (threadIdx.x >> 6);
    if (d >= n) return;
    int lane = threadIdx.x & 63;
    int p = row[d], end = row[d + 1];
    int deg = end - p;
    float degf = (float)(deg > 1 ? deg : 1);
    float dd = rsqrtf(degf);
    float sq = sqrtf(degf);
    float f0 = __half2float(h16[(long)d * 64 + lane]) * sq;
    float f1 = __half2float(g16[(long)d * 64 + lane]) * sq;
    float a0 = 0.f, a1 = 0.f, a2 = 0.f, a3 = 0.f;
    for (; p + 8 <= end; p += 8) {
        int s0 = esrc[p], s1 = esrc[p + 1], s2 = esrc[p + 2], s3 = esrc[p + 3];
        int s4 = esrc[p + 4], s5 = esrc[p + 5], s6 = esrc[p + 6], s7 = esrc[p + 7];
        a0 += __half2float(g16[(long)s0 * 64 + lane]);
        a1 += __half2float(g16[(long)s1 * 64 + lane]);
        a2 += __half2float(g16[(long)s2 * 64 + lane]);
        a3 += __half2float(g16[(long)s3 * 64 + lane]);
        a0 += __half2float(g16[(long)s4 * 64 + lane]);
        a1 += __half2float(g16[(long)s5 * 64 + lane]);
        a2 += __half2float(g16[(long)s6 * 64 + lane]);
        a3 += __half2float(g16[(long)s7 * 64 + lane]);
    }
    for (; p < end; ++p) {
        int s = esrc[p];
        a0 += __half2float(g16[(long)s * 64 + lane]);
    }
    float acc = (a0 + a1) + (a2 + a3);
    float f2 = f1 - acc * dd;
    long ob = (long)d * 384 + lane;
    if (g == 0) {
        hall[ob]       = 3.0f * f0 - 3.0f * f1 + 0.75f * f2;
        hall[ob + 64]  = 3.0f * f1 - 1.5f * f2;
        hall[ob + 128] = 0.75f * f2;
    } else {
        float ss = 4.0f * (f0 + f1 + f2);
        hall[ob + 192] = ss; hall[ob + 256] = ss; hall[ob + 320] = ss;
    }
}

// ---------- fallback path (ws too small for fp16 shadows) ----------
__global__ __launch_bounds__(256) void gather2_kernel(
    const int* __restrict__ row_o, const int* __restrict__ esrc_o, const float* __restrict__ dinv_o,
    const int* __restrict__ row_s, const int* __restrict__ esrc_s, const float* __restrict__ dinv_s,
    float* __restrict__ hall, int in_off_o, int in_off_s, int n, int nb) {
    int b = blockIdx.x;
    const int* row; const int* esrc; const float* dinv; int in_off;
    if (b < nb) { row = row_o; esrc = esrc_o; dinv = dinv_o; in_off = in_off_o; }
    else { b -= nb; row = row_s; esrc = esrc_s; dinv = dinv_s; in_off = in_off_s; }
    int d = b * 4 + (threadIdx.x >> 6);
    if (d >= n) return;
    int lane = threadIdx.x & 63;
    int p = row[d], end = row[d + 1];
    const float* fin = hall + in_off;
    float a0 = 0.f, a1 = 0.f, a2 = 0.f, a3 = 0.f;
    for (; p + 4 <= end; p += 4) {
        int s0 = esrc[p], s1 = esrc[p + 1], s2 = esrc[p + 2], s3 = esrc[p + 3];
        a0 = fmaf(fin[(long)s0 * 384 + lane], dinv[s0], a0);
        a1 = fmaf(fin[(long)s1 * 384 + lane], dinv[s1], a1);
        a2 = fmaf(fin[(long)s2 * 384 + lane], dinv[s2], a2);
        a3 = fmaf(fin[(long)s3 * 384 + lane], dinv[s3], a3);
    }
    for (; p < end; ++p) {
        int s = esrc[p];
        a0 = fmaf(fin[(long)s * 384 + lane], dinv[s], a0);
    }
    float acc = (a0 + a1) + (a2 + a3);
    long ob = (long)d * 384 + lane;
    hall[ob + in_off + 64] = fin[ob] - acc * dinv[d];
}

__global__ __launch_bounds__(256) void combine_kernel(float* __restrict__ h, int nf) {
    int i = blockIdx.x * 256 + threadIdx.x;
    if (i >= nf) return;
    long ob = (long)(i >> 6) * 384 + (i & 63);
    float f0v = h[ob], f1v = h[ob + 64], f2v = h[ob + 128];
    h[ob]       = 3.0f * f0v - 3.0f * f1v + 0.75f * f2v;
    h[ob + 64]  = 3.0f * f1v - 1.5f * f2v;
    h[ob + 128] = 0.75f * f2v;
    float ss = 4.0f * (h[ob + 192] + h[ob + 256] + h[ob + 320]);
    h[ob + 192] = ss; h[ob + 256] = ss; h[ob + 320] = ss;
}
// -------------------------------------------------------------------

// logits = relu(h_all @ Wm1f + bm1) @ Wm2 + bm2. K=256 (sim slots folded):
// reads only floats 0..255 of each hall row (o0,o1,o2,s).
__global__ __launch_bounds__(256) void mlp_kernel(
    const float* __restrict__ hall, const float* __restrict__ w1f,
    const float* __restrict__ bm1, const float* __restrict__ Wm2,
    const float* __restrict__ bm2, float* __restrict__ logits, int n) {
    __shared__ float xs[64][132];
    __shared__ float Wf[128][68];
    int tid = threadIdx.x;
    int node0 = blockIdx.x * 64;
    int tx = tid & 15, ty = tid >> 4;
    float acc[4][4] = {};
    const float4* wsrc = (const float4*)w1f;
    const float4* hsrc = (const float4*)hall;
    for (int c = 0; c < 2; ++c) {
        __syncthreads();
        for (int i = tid; i < 2048; i += 256)
            *(float4*)&Wf[i >> 4][(i & 15) * 4] = wsrc[c * 2048 + i];
        for (int i = tid; i < 2048; i += 256) {
            int nl = i >> 5, cc = i & 31;
            int node = node0 + nl;
            float4 v = make_float4(0.f, 0.f, 0.f, 0.f);
            if (node < n) v = hsrc[(long)node * 96 + c * 32 + cc];
            *(float4*)&xs[nl][cc * 4] = v;
        }
        __syncthreads();
        #pragma unroll 2
        for (int k = 0; k < 128; k += 4) {
            float4 a[4], bb[4];
            #pragma unroll
            for (int i = 0; i < 4; ++i) a[i] = *(const float4*)&xs[ty * 4 + i][k];
            #pragma unroll
            for (int j = 0; j < 4; ++j) bb[j] = *(const float4*)&Wf[k + j][tx * 4];
            #pragma unroll
            for (int i = 0; i < 4; ++i) {
                acc[i][0] = fmaf(a[i].x, bb[0].x, acc[i][0]);
                acc[i][1] = fmaf(a[i].x, bb[0].y, acc[i][1]);
                acc[i][2] = fmaf(a[i].x, bb[0].z, acc[i][2]);
                acc[i][3] = fmaf(a[i].x, bb[0].w, acc[i][3]);
                acc[i][0] = fmaf(a[i].y, bb[1].x, acc[i][0]);
                acc[i][1] = fmaf(a[i].y, bb[1].y, acc[i][1]);
                acc[i][2] = fmaf(a[i].y, bb[1].z, acc[i][2]);
                acc[i][3] = fmaf(a[i].y, bb[1].w, acc[i][3]);
                acc[i][0] = fmaf(a[i].z, bb[2].x, acc[i][0]);
                acc[i][1] = fmaf(a[i].z, bb[2].y, acc[i][1]);
                acc[i][2] = fmaf(a[i].z, bb[2].z, acc[i][2]);
                acc[i][3] = fmaf(a[i].z, bb[2].w, acc[i][3]);
                acc[i][0] = fmaf(a[i].w, bb[3].x, acc[i][0]);
                acc[i][1] = fmaf(a[i].w, bb[3].y, acc[i][1]);
                acc[i][2] = fmaf(a[i].w, bb[3].z, acc[i][2]);
                acc[i][3] = fmaf(a[i].w, bb[3].w, acc[i][3]);
            }
        }
    }
    __syncthreads();
    float4 bias = *(const float4*)&bm1[tx * 4];
    #pragma unroll
    for (int i = 0; i < 4; ++i) {
        xs[ty * 4 + i][tx * 4 + 0] = fmaxf(acc[i][0] + bias.x, 0.0f);
        xs[ty * 4 + i][tx * 4 + 1] = fmaxf(acc[i][1] + bias.y, 0.0f);
        xs[ty * 4 + i][tx * 4 + 2] = fmaxf(acc[i][2] + bias.z, 0.0f);
        xs[ty * 4 + i][tx * 4 + 3] = fmaxf(acc[i][3] + bias.w, 0.0f);
    }
    __syncthreads();
    if (tid < 128) {
        int nl = tid >> 1, o = tid & 1;
        int node = node0 + nl;
        if (node < n) {
            float p = bm2[o];
            #pragma unroll 8
            for (int k = 0; k < 64; ++k) p = fmaf(xs[nl][k], Wm2[k * 2 + o], p);
            logits[(long)node * 2 + o] = p;
        }
    }
}

extern "C" void kernel_launch(void* const* d_in, const int* in_sizes, int n_in,
                              void* d_out, int out_size, void* d_ws, size_t ws_size,
                              hipStream_t stream) {
    const float* x     = (const float*)d_in[0];
    const float* sim_x = (const float*)d_in[1];
    const int* src     = (const int*)d_in[2];
    const int* dst     = (const int*)d_in[3];
    const int* sim_src = (const int*)d_in[4];
    const int* sim_dst = (const int*)d_in[5];
    const float* W1_o = (const float*)d_in[6];
    const float* b1_o = (const float*)d_in[7];
    const float* W1_s = (const float*)d_in[8];
    const float* b1_s = (const float*)d_in[9];
    const float* Wm1  = (const float*)d_in[10];
    const float* bm1  = (const float*)d_in[11];
    const float* Wm2  = (const float*)d_in[12];
    const float* bm2  = (const float*)d_in[13];

    const int N  = in_sizes[0] / 128;  // 50000
    const int E  = in_sizes[2];        // 800000
    const int Es = in_sizes[4];
    const int NF = N * 64;
    const int K  = (N + (1 << KB_BITS) - 1) >> KB_BITS;  // 1024-node buckets

    float* hall = (float*)d_out;                 // N x 384
    float* lgt  = hall + (long)N * 384;          // N x 2
    float* dinv = lgt;                           // [dinv_o N | dinv_s N] until MLP
    float* dinv_o = dinv;
    float* dinv_s = dinv + N;

    int* row_o  = (int*)d_ws;            // N+1
    int* row_s  = row_o + (N + 1);       // N+1
    int* esrc_o = row_s + (N + 1);       // E
    int* esrc_s = esrc_o + E;            // Es
    int* bhist  = esrc_s + Es;           // 2*KMAX
    int* brow   = bhist + 2 * KMAX;      // 2*(KMAX+1)
    int* gcur   = brow + 2 * (KMAX + 1); // 2*KMAX
    float* w1f  = (float*)(gcur + 2 * KMAX);     // 256*64
    __half* h16_o = (__half*)(w1f + 256 * 64);   // N*64 halves each
    __half* h16_s = h16_o + (long)N * 64;
    __half* g16_o = h16_s + (long)N * 64;
    __half* g16_s = g16_o + (long)N * 64;
    size_t need_f16 = (size_t)((char*)(g16_s + (long)N * 64) - (char*)d_ws);
    bool f16path = ws_size >= need_f16;
    // staged[E+Es] aliases h16 region: consumed by place BEFORE in_gemm writes h16.
    unsigned* staged = (unsigned*)h16_o;

    int nb4  = (N + 3) / 4;
    int nbq  = (nb4 + 3) / 4;
    int nb64 = (N + 63) / 64;
    int nfb  = (NF + 255) / 256;
    int nbo  = (E + PCHUNK - 1) / PCHUNK;
    int nbs  = (Es + PCHUNK - 1) / PCHUNK;

    // ---- CSR build: hist -> bases -> LDS radix partition -> per-bucket place ----
    hipMemsetAsync(bhist, 0, (size_t)(2 * KMAX) * sizeof(int), stream);
    fold_kernel<<<64, 256, 0, stream>>>(Wm1, w1f);
    bhist_kernel<<<256, 256, 0, stream>>>(dst, sim_dst, bhist, E, Es);
    bscan_kernel<<<1, 128, 0, stream>>>(bhist, brow, gcur);
    partition_kernel<<<nbo + nbs, 256, 0, stream>>>(src, dst, sim_src, sim_dst,
                                                    gcur, staged, E, Es, nbo);
    place_kernel<<<2 * K, 512, 0, stream>>>(staged, brow, row_o, row_s,
                                            esrc_o, esrc_s, dinv, N, K, E);

    // ---- input GEMMs: f16path writes only premul fp16 shadows ----
    in_gemm_kernel<<<nb64, 256, 0, stream>>>(x, W1_o, b1_o,
                                             f16path ? (float*)nullptr : hall, 0,
                                             f16path ? h16_o : (__half*)nullptr, dinv_o, N);
    in_gemm_kernel<<<nb64, 256, 0, stream>>>(sim_x, W1_s, b1_s,
                                             f16path ? (float*)nullptr : hall, 192,
                                             f16path ? h16_s : (__half*)nullptr, dinv_s, N);

    if (f16path) {
        hop1_kernel<<<nbq * 8, 256, 0, stream>>>(row_o, esrc_o, row_s, esrc_s,
                                                 h16_o, h16_s, g16_o, g16_s, N, nb4);
        hop2_kernel<<<nbq * 8, 256, 0, stream>>>(row_o, esrc_o, row_s, esrc_s,
                                                 h16_o, h16_s, g16_o, g16_s,
                                                 hall, N, nb4);
    } else {
        gather2_kernel<<<2 * nb4, 256, 0, stream>>>(row_o, esrc_o, dinv_o,
                                                    row_s, esrc_s, dinv_s,
                                                    hall, 0, 192, N, nb4);
        gather2_kernel<<<2 * nb4, 256, 0, stream>>>(row_o, esrc_o, dinv_o,
                                                    row_s, esrc_s, dinv_s,
                                                    hall, 64, 256, N, nb4);
        combine_kernel<<<nfb, 256, 0, stream>>>(hall, NF);
    }

    // ---- MLP head (folded K=256; overwrites dinv stash with logits) ----
    mlp_kernel<<<nb64, 256, 0, stream>>>(hall, w1f, bm1, Wm2, bm2, lgt, N);
}